// Round 8
// baseline (4259.170 us; speedup 1.0000x reference)
//
#include <hip/hip_runtime.h>
#include <hip/hip_bf16.h>
#include <stdint.h>

#define H 2048
#define FOURH 8192
#define NT 768
#define NS 256

typedef __attribute__((ext_vector_type(8))) short bf16x8;
typedef __attribute__((ext_vector_type(4))) float f32x4;
typedef __attribute__((ext_vector_type(4))) unsigned uint4v;

static __device__ __forceinline__ unsigned short f2bf(float x) {
  unsigned u = __float_as_uint(x);
  return (unsigned short)((u + 0x7fffu + ((u >> 16) & 1u)) >> 16);
}
static __device__ __forceinline__ unsigned pk2(float lo, float hi) {
  return ((unsigned)f2bf(hi) << 16) | (unsigned)f2bf(lo);
}
static __device__ __forceinline__ float bflo(unsigned u) { return __uint_as_float(u << 16); }
static __device__ __forceinline__ float bfhi(unsigned u) { return __uint_as_float(u & 0xffff0000u); }
static __device__ __forceinline__ float sigm(float x) { return 1.f / (1.f + __expf(-x)); }
static __device__ __forceinline__ float tanh_fast(float x) {
  float xc = fminf(fmaxf(x, -15.f), 15.f);
  float e = __expf(2.f * xc);
  return (e - 1.f) / (e + 1.f);
}

// ---------------- gather: build X_bf16[768][2048] ----------------
__global__ void gather_x(const int* __restrict__ ctx, const int* __restrict__ f1,
                         const int* __restrict__ f2, const float* __restrict__ ctx_table,
                         const float* __restrict__ face_table, unsigned short* __restrict__ X) {
  int t = blockIdx.x;            // 0..767
  int s = t / 3, k = t - 3 * s;  // sample, sub-step
  const float* src;
  if (k == 0)      src = ctx_table  + (size_t)ctx[s] * H;
  else if (k == 1) src = face_table + (size_t)f1[s] * H;
  else             src = face_table + (size_t)f2[s] * H;
  int c = threadIdx.x * 8;
  float4 v0 = *(const float4*)(src + c);
  float4 v1 = *(const float4*)(src + c + 4);
  uint4 o;
  o.x = pk2(v0.x, v0.y); o.y = pk2(v0.z, v0.w);
  o.z = pk2(v1.x, v1.y); o.w = pk2(v1.z, v1.w);
  *(uint4*)(X + (size_t)t * H + c) = o;
}

// ---------------- GEMM: P[768][8192] = X @ W_ih^T + (b_ih + b_hh) ----------------
__launch_bounds__(256)
__global__ void gemm_p(const unsigned short* __restrict__ X, const float* __restrict__ Wih,
                       const float* __restrict__ bih, const float* __restrict__ bhh,
                       float* __restrict__ P) {
  __shared__ unsigned short Alds[128 * 32];
  __shared__ unsigned short Blds[128 * 32];
  int tid = threadIdx.x;
  int bm = (blockIdx.x >> 6) * 128;   // 6 M-tiles
  int bn = (blockIdx.x & 63) * 128;   // 64 N-tiles
  int w = tid >> 6, l = tid & 63;
  int wm = (w >> 1) * 64, wn = (w & 1) * 64;
  int sr = tid >> 1;             // staging row 0..127
  int sc = (tid & 1) * 16;       // staging col 0 / 16
  int cl = l & 15, kg = (l >> 4) * 8;

  f32x4 acc[4][4];
#pragma unroll
  for (int i = 0; i < 4; ++i)
#pragma unroll
    for (int j = 0; j < 4; ++j) acc[i][j] = (f32x4){0.f, 0.f, 0.f, 0.f};

  for (int kt = 0; kt < H; kt += 32) {
    __syncthreads();
    const unsigned short* ap = X + (size_t)(bm + sr) * H + kt + sc;
    uint4 a0 = *(const uint4*)ap;
    uint4 a1 = *(const uint4*)(ap + 8);
    const float* bp = Wih + (size_t)(bn + sr) * H + kt + sc;
    float4 f0 = *(const float4*)bp;
    float4 f1v = *(const float4*)(bp + 4);
    float4 f2v = *(const float4*)(bp + 8);
    float4 f3v = *(const float4*)(bp + 12);
    *(uint4*)(Alds + sr * 32 + sc) = a0;
    *(uint4*)(Alds + sr * 32 + sc + 8) = a1;
    uint4 b0, b1;
    b0.x = pk2(f0.x, f0.y);  b0.y = pk2(f0.z, f0.w);
    b0.z = pk2(f1v.x, f1v.y); b0.w = pk2(f1v.z, f1v.w);
    b1.x = pk2(f2v.x, f2v.y); b1.y = pk2(f2v.z, f2v.w);
    b1.z = pk2(f3v.x, f3v.y); b1.w = pk2(f3v.z, f3v.w);
    *(uint4*)(Blds + sr * 32 + sc) = b0;
    *(uint4*)(Blds + sr * 32 + sc + 8) = b1;
    __syncthreads();

    bf16x8 af[4], bb[4];
#pragma unroll
    for (int i = 0; i < 4; ++i) {
      af[i] = *(bf16x8*)(Alds + (wm + i * 16 + cl) * 32 + kg);
      bb[i] = *(bf16x8*)(Blds + (wn + i * 16 + cl) * 32 + kg);
    }
#pragma unroll
    for (int i = 0; i < 4; ++i)
#pragma unroll
      for (int j = 0; j < 4; ++j)
        acc[i][j] = __builtin_amdgcn_mfma_f32_16x16x32_bf16(af[i], bb[j], acc[i][j], 0, 0, 0);
  }

  int rg = (l >> 4) * 4;
#pragma unroll
  for (int j = 0; j < 4; ++j) {
    int n = bn + wn + j * 16 + cl;
    float bias = bih[n] + bhh[n];
#pragma unroll
    for (int i = 0; i < 4; ++i) {
      int m = bm + wm + i * 16 + rg;
#pragma unroll
      for (int r = 0; r < 4; ++r)
        P[(size_t)(m + r) * FOURH + n] = acc[i][j][r] + bias;
    }
  }
}

// ---------------- persistent sequential LSTM ----------------
// R7 push-replication structure + COUNTER-GATED POLLING.
// hrep[8][2][2048] u32 = (tag16<<16 | bf16(h)): producers push their 8 tagged
// words to all 8 replicas (lanes 0..7 of wave 0, 2x dwordx4 sc0 sc1 each).
// NEW: hcnt[8] counter lines (256B each, 8 subcounters u32). After the data
// push, lane r atomically bumps subcounter (g>>5) of replica r. Consumers:
// ONLY wave 0 polls its replica's single counter line (uniform address -> 1
// line-request/WG/round, ~32 req/line/round chip-wide) until all 8
// subcounters reach 32*t, then the WG does ONE tag-verified data sweep.
// The counter is a HINT (relaxed store->add ordering): the tag-retry loop
// remains the correctness net, it just no longer runs continuously, so the
// LLC serves the real data read from an empty queue.
__launch_bounds__(256, 1)
__global__ void lstm_seq(const float* __restrict__ Whh, const float* __restrict__ P,
                         unsigned* __restrict__ hrep, unsigned* __restrict__ hcnt,
                         float* __restrict__ hs, float* __restrict__ out) {
  __shared__ float h_lds[H];
  __shared__ float gates_lds[2][32];
  int g = blockIdx.x;
  int tid = threadIdx.x;
  int G = tid >> 6, l = tid & 63;

  // one-time weight load: rows G*2048 + g*8 + q, cols j*256 + l*4 + 0..3
  unsigned wpk[8][8][2];
#pragma unroll
  for (int q = 0; q < 8; ++q) {
    const float* wrow = Whh + (size_t)(G * H + g * 8 + q) * H;
#pragma unroll
    for (int j = 0; j < 8; ++j) {
      float4 wv = *(const float4*)(wrow + j * 256 + l * 4);
      wpk[q][j][0] = pk2(wv.x, wv.y);
      wpk[q][j][1] = pk2(wv.z, wv.w);
    }
  }

  float c_state = 0.f;  // valid on wave-0 lanes 0..7
  const unsigned* myrep = hrep + (size_t)(g & 7) * 2 * H;
  const unsigned* mycnt = hcnt + (size_t)(g & 7) * 64;  // 256B line

  for (int t = 0; t < NT; ++t) {
    // independent P-row fetch first (overlaps the wait); wave 0 only
    float p_v = 0.f;
    if (tid < 32)
      p_v = P[(size_t)t * FOURH + (size_t)(tid >> 3) * H + g * 8 + (tid & 7)];

    // ---- counter gate: wave 0 polls the single counter line ----
    if (t > 0 && tid < 64) {
      unsigned need = 32u * (unsigned)t;
      uint4v c0, c1;
      for (;;) {
        asm volatile(
            "global_load_dwordx4 %0, %2, off sc0 sc1\n\t"
            "global_load_dwordx4 %1, %3, off sc0 sc1\n\t"
            "s_waitcnt vmcnt(0)"
            : "=&v"(c0), "=&v"(c1)
            : "v"(mycnt), "v"(mycnt + 4)
            : "memory");
        if (c0.x >= need && c0.y >= need && c0.z >= need && c0.w >= need &&
            c1.x >= need && c1.y >= need && c1.z >= need && c1.w >= need)
          break;
        __builtin_amdgcn_s_sleep(2);
      }
    }
    __syncthreads();

    // ---- one tag-verified data sweep (retry is the rare safety path) ----
    {
      const unsigned* src = myrep + (size_t)(t & 1) * H + tid * 8;
      unsigned want = ((unsigned)t & 0xffffu) << 16;
      uint4v a, b;
      for (;;) {
        asm volatile(
            "global_load_dwordx4 %0, %2, off sc0 sc1\n\t"
            "global_load_dwordx4 %1, %3, off sc0 sc1\n\t"
            "s_waitcnt vmcnt(0)"
            : "=&v"(a), "=&v"(b)
            : "v"(src), "v"(src + 4)
            : "memory");
        unsigned m = ((a.x ^ want) | (a.y ^ want) | (a.z ^ want) | (a.w ^ want) |
                      (b.x ^ want) | (b.y ^ want) | (b.z ^ want) | (b.w ^ want)) &
                     0xffff0000u;
        if (m == 0) break;
        __builtin_amdgcn_s_sleep(1);
      }
      *(float4*)&h_lds[tid * 8] =
          make_float4(__uint_as_float(a.x << 16), __uint_as_float(a.y << 16),
                      __uint_as_float(a.z << 16), __uint_as_float(a.w << 16));
      *(float4*)&h_lds[tid * 8 + 4] =
          make_float4(__uint_as_float(b.x << 16), __uint_as_float(b.y << 16),
                      __uint_as_float(b.z << 16), __uint_as_float(b.w << 16));
    }
    __syncthreads();

    // matvec: 8 rows x 32 cols per thread
    float acc[8] = {0.f, 0.f, 0.f, 0.f, 0.f, 0.f, 0.f, 0.f};
#pragma unroll
    for (int j = 0; j < 8; ++j) {
      float4 hj = *(float4*)&h_lds[j * 256 + l * 4];
#pragma unroll
      for (int q = 0; q < 8; ++q) {
        unsigned u0 = wpk[q][j][0], u1 = wpk[q][j][1];
        acc[q] += bflo(u0) * hj.x + bfhi(u0) * hj.y + bflo(u1) * hj.z + bfhi(u1) * hj.w;
      }
    }
    // butterfly reduce over the wave (cols)
#pragma unroll
    for (int q = 0; q < 8; ++q) {
      float v2 = acc[q];
#pragma unroll
      for (int off = 1; off < 64; off <<= 1) v2 += __shfl_xor(v2, off, 64);
      acc[q] = v2;
    }
    if (l == 0) {
#pragma unroll
      for (int q = 0; q < 8; ++q) gates_lds[t & 1][G * 8 + q] = acc[q];
    }

    // wave 0: distribute the 4 gate biases of row (g*8 + tid&7) via shfl
    float pre_i = 0.f, pre_f = 0.f, pre_g = 0.f, pre_o = 0.f;
    if (tid < 64) {
      int q = tid & 7;
      pre_i = __shfl(p_v, q, 64);
      pre_f = __shfl(p_v, 8 + q, 64);
      pre_g = __shfl(p_v, 16 + q, 64);
      pre_o = __shfl(p_v, 24 + q, 64);
    }
    __syncthreads();

    // wave 0: gate finish on lanes 0..7, PUSH to all 8 replicas, bump counters
    if (tid < 64) {
      unsigned wword = 0;
      if (l < 8) {
        int q = l;
        float iv = sigm(gates_lds[t & 1][q]      + pre_i);
        float fv = sigm(gates_lds[t & 1][8 + q]  + pre_f);
        float gv = tanh_fast(gates_lds[t & 1][16 + q] + pre_g);
        float ov = sigm(gates_lds[t & 1][24 + q] + pre_o);
        c_state = fv * c_state + iv * gv;
        float hnew = ov * tanh_fast(c_state);
        wword = ((((unsigned)(t + 1)) & 0xffffu) << 16) | (unsigned)f2bf(hnew);
        int m3 = t - (t / 3) * 3;
        if (m3 == 2) hs[(size_t)(t / 3) * H + g * 8 + q] = hnew;
        if (t == NT - 1) {
          out[512 + g * 8 + q] = hnew;        // hF
          out[512 + H + g * 8 + q] = c_state; // cF
        }
      }
      unsigned w0 = __shfl(wword, 0, 64), w1 = __shfl(wword, 1, 64);
      unsigned w2 = __shfl(wword, 2, 64), w3 = __shfl(wword, 3, 64);
      unsigned w4 = __shfl(wword, 4, 64), w5 = __shfl(wword, 5, 64);
      unsigned w6 = __shfl(wword, 6, 64), w7 = __shfl(wword, 7, 64);
      if (l < 8) {
        // lane r pushes the WG's full 8-word slot into replica r
        unsigned* dst = hrep + ((size_t)l * 2 + ((t + 1) & 1)) * H + g * 8;
        uint4v A, B;
        A.x = w0; A.y = w1; A.z = w2; A.w = w3;
        B.x = w4; B.y = w5; B.z = w6; B.w = w7;
        asm volatile(
            "global_store_dwordx4 %0, %2, off sc0 sc1\n\t"
            "global_store_dwordx4 %1, %3, off sc0 sc1"
            :
            : "v"(dst), "v"(dst + 4), "v"(A), "v"(B)
            : "memory");
        // hint: bump subcounter (g>>5) of replica l (relaxed, no return)
        __hip_atomic_fetch_add(&hcnt[(size_t)l * 64 + (g >> 5)], 1u,
                               __ATOMIC_RELAXED, __HIP_MEMORY_SCOPE_AGENT);
      }
    }
  }
}

// ---------------- readout: outputs[256][2] ----------------
__global__ void out_head(const float* __restrict__ hs, const float* __restrict__ Wout,
                         const float* __restrict__ bout, float* __restrict__ out) {
  int s = blockIdx.x;
  int l = threadIdx.x;  // 64
  float a0 = 0.f, a1 = 0.f;
#pragma unroll 4
  for (int j = 0; j < 32; ++j) {
    int idx = j * 64 + l;
    float h = hs[(size_t)s * H + idx];
    a0 += h * Wout[idx];
    a1 += h * Wout[H + idx];
  }
#pragma unroll
  for (int off = 1; off < 64; off <<= 1) {
    a0 += __shfl_xor(a0, off, 64);
    a1 += __shfl_xor(a1, off, 64);
  }
  if (l == 0) {
    out[s * 2]     = a0 + bout[0];
    out[s * 2 + 1] = a1 + bout[1];
  }
}

extern "C" void kernel_launch(void* const* d_in, const int* in_sizes, int n_in,
                              void* d_out, int out_size, void* d_ws, size_t ws_size,
                              hipStream_t stream) {
  const int*   ctx        = (const int*)d_in[0];
  const int*   f1         = (const int*)d_in[1];
  const int*   f2         = (const int*)d_in[2];
  const float* ctx_table  = (const float*)d_in[3];
  const float* face_table = (const float*)d_in[4];
  const float* Wih        = (const float*)d_in[5];
  const float* Whh        = (const float*)d_in[6];
  const float* bih        = (const float*)d_in[7];
  const float* bhh        = (const float*)d_in[8];
  const float* Wout       = (const float*)d_in[9];
  const float* bout       = (const float*)d_in[10];
  float* out = (float*)d_out;

  char* ws = (char*)d_ws;
  size_t off = 0;
  unsigned short* X = (unsigned short*)(ws + off); off += (size_t)NT * H * 2;  // 3,145,728
  float* P    = (float*)(ws + off); off += (size_t)NT * FOURH * 4;             // 25,165,824
  unsigned* hrep = (unsigned*)(ws + off); off += (size_t)8 * 2 * H * 4;        // 131,072
  unsigned* hcnt = (unsigned*)(ws + off); off += (size_t)8 * 256;              // 2,048
  float* hs   = (float*)(ws + off); off += (size_t)NS * H * 4;                 // 2,097,152

  // zero replicas (parity-0 tag0/value0 = valid t=0 data) and counters;
  // replay-safe (captured in the graph)
  hipMemsetAsync(hrep, 0, (size_t)8 * 2 * H * 4, stream);
  hipMemsetAsync(hcnt, 0, (size_t)8 * 256, stream);

  gather_x<<<NT, 256, 0, stream>>>(ctx, f1, f2, ctx_table, face_table, X);
  gemm_p<<<6 * 64, 256, 0, stream>>>(X, Wih, bih, bhh, P);
  lstm_seq<<<NS, 256, 0, stream>>>(Whh, P, hrep, hcnt, hs, out);
  out_head<<<NS, 64, 0, stream>>>(hs, Wout, bout, out);
}

// Round 9
// 3208.030 us; speedup vs baseline: 1.3277x; 1.3277x over previous
//
#include <hip/hip_runtime.h>
#include <hip/hip_bf16.h>
#include <stdint.h>

#define H 2048
#define FOURH 8192
#define NT 768
#define NS 256

typedef __attribute__((ext_vector_type(8))) short bf16x8;
typedef __attribute__((ext_vector_type(4))) float f32x4;
typedef __attribute__((ext_vector_type(4))) unsigned uint4v;

static __device__ __forceinline__ unsigned short f2bf(float x) {
  unsigned u = __float_as_uint(x);
  return (unsigned short)((u + 0x7fffu + ((u >> 16) & 1u)) >> 16);
}
static __device__ __forceinline__ unsigned pk2(float lo, float hi) {
  return ((unsigned)f2bf(hi) << 16) | (unsigned)f2bf(lo);
}
static __device__ __forceinline__ float bflo(unsigned u) { return __uint_as_float(u << 16); }
static __device__ __forceinline__ float bfhi(unsigned u) { return __uint_as_float(u & 0xffff0000u); }
static __device__ __forceinline__ float sigm(float x) { return 1.f / (1.f + __expf(-x)); }
static __device__ __forceinline__ float tanh_fast(float x) {
  float xc = fminf(fmaxf(x, -15.f), 15.f);
  float e = __expf(2.f * xc);
  return (e - 1.f) / (e + 1.f);
}

// ---------------- gather: build X_bf16[768][2048] ----------------
__global__ void gather_x(const int* __restrict__ ctx, const int* __restrict__ f1,
                         const int* __restrict__ f2, const float* __restrict__ ctx_table,
                         const float* __restrict__ face_table, unsigned short* __restrict__ X) {
  int t = blockIdx.x;            // 0..767
  int s = t / 3, k = t - 3 * s;  // sample, sub-step
  const float* src;
  if (k == 0)      src = ctx_table  + (size_t)ctx[s] * H;
  else if (k == 1) src = face_table + (size_t)f1[s] * H;
  else             src = face_table + (size_t)f2[s] * H;
  int c = threadIdx.x * 8;
  float4 v0 = *(const float4*)(src + c);
  float4 v1 = *(const float4*)(src + c + 4);
  uint4 o;
  o.x = pk2(v0.x, v0.y); o.y = pk2(v0.z, v0.w);
  o.z = pk2(v1.x, v1.y); o.w = pk2(v1.z, v1.w);
  *(uint4*)(X + (size_t)t * H + c) = o;
}

// ---------------- GEMM: P[768][8192] = X @ W_ih^T + (b_ih + b_hh) ----------------
__launch_bounds__(256)
__global__ void gemm_p(const unsigned short* __restrict__ X, const float* __restrict__ Wih,
                       const float* __restrict__ bih, const float* __restrict__ bhh,
                       float* __restrict__ P) {
  __shared__ unsigned short Alds[128 * 32];
  __shared__ unsigned short Blds[128 * 32];
  int tid = threadIdx.x;
  int bm = (blockIdx.x >> 6) * 128;   // 6 M-tiles
  int bn = (blockIdx.x & 63) * 128;   // 64 N-tiles
  int w = tid >> 6, l = tid & 63;
  int wm = (w >> 1) * 64, wn = (w & 1) * 64;
  int sr = tid >> 1;             // staging row 0..127
  int sc = (tid & 1) * 16;       // staging col 0 / 16
  int cl = l & 15, kg = (l >> 4) * 8;

  f32x4 acc[4][4];
#pragma unroll
  for (int i = 0; i < 4; ++i)
#pragma unroll
    for (int j = 0; j < 4; ++j) acc[i][j] = (f32x4){0.f, 0.f, 0.f, 0.f};

  for (int kt = 0; kt < H; kt += 32) {
    __syncthreads();
    const unsigned short* ap = X + (size_t)(bm + sr) * H + kt + sc;
    uint4 a0 = *(const uint4*)ap;
    uint4 a1 = *(const uint4*)(ap + 8);
    const float* bp = Wih + (size_t)(bn + sr) * H + kt + sc;
    float4 f0 = *(const float4*)bp;
    float4 f1v = *(const float4*)(bp + 4);
    float4 f2v = *(const float4*)(bp + 8);
    float4 f3v = *(const float4*)(bp + 12);
    *(uint4*)(Alds + sr * 32 + sc) = a0;
    *(uint4*)(Alds + sr * 32 + sc + 8) = a1;
    uint4 b0, b1;
    b0.x = pk2(f0.x, f0.y);  b0.y = pk2(f0.z, f0.w);
    b0.z = pk2(f1v.x, f1v.y); b0.w = pk2(f1v.z, f1v.w);
    b1.x = pk2(f2v.x, f2v.y); b1.y = pk2(f2v.z, f2v.w);
    b1.z = pk2(f3v.x, f3v.y); b1.w = pk2(f3v.z, f3v.w);
    *(uint4*)(Blds + sr * 32 + sc) = b0;
    *(uint4*)(Blds + sr * 32 + sc + 8) = b1;
    __syncthreads();

    bf16x8 af[4], bb[4];
#pragma unroll
    for (int i = 0; i < 4; ++i) {
      af[i] = *(bf16x8*)(Alds + (wm + i * 16 + cl) * 32 + kg);
      bb[i] = *(bf16x8*)(Blds + (wn + i * 16 + cl) * 32 + kg);
    }
#pragma unroll
    for (int i = 0; i < 4; ++i)
#pragma unroll
      for (int j = 0; j < 4; ++j)
        acc[i][j] = __builtin_amdgcn_mfma_f32_16x16x32_bf16(af[i], bb[j], acc[i][j], 0, 0, 0);
  }

  int rg = (l >> 4) * 4;
#pragma unroll
  for (int j = 0; j < 4; ++j) {
    int n = bn + wn + j * 16 + cl;
    float bias = bih[n] + bhh[n];
#pragma unroll
    for (int i = 0; i < 4; ++i) {
      int m = bm + wm + i * 16 + rg;
#pragma unroll
      for (int r = 0; r < 4; ++r)
        P[(size_t)(m + r) * FOURH + n] = acc[i][j][r] + bias;
    }
  }
}

// ---------------- persistent sequential LSTM ----------------
// R7 push-replication + FINE-GRAINED ARRIVAL OVERLAP (no __syncthreads in the
// step loop). hrep[8][2][2048] u32 = (tag16<<16 | bf16(h)); producers (wave 0
// lanes 0..7) push the WG's 8 tagged words to all 8 replicas (2x dwordx4
// sc0 sc1 each). Thread tid's polled slice == producer-WG tid's output, so
// each thread independently: detects its slice -> writes h_lds[parity] ->
// LDS-atomicAdd(ready[parity][tid>>5]) (release). Matvec waves acquire-spin
// per 256-col block j until ready[parity][j] hits 32*epoch, consuming blocks
// as they arrive -- the slowest producer's block is processed last, so its
// detect latency overlaps the other 7/8 of the matvec. gates handoff via
// gcnt[parity] (4*epoch). All counters monotonic (epoch = t/2+1): no resets,
// parity double-buffer keeps cross-step LDS reuse race-free (induction: a
// thread writes parity p for step t+1 only after its own WG stored t+1,
// which requires gcnt==4*epoch(t), i.e. every wave finished step t matvec
// and its step t-1 reads long before).
__launch_bounds__(256, 1)
__global__ void lstm_seq(const float* __restrict__ Whh, const float* __restrict__ P,
                         unsigned* __restrict__ hrep, float* __restrict__ hs,
                         float* __restrict__ out) {
  __shared__ float h_lds[2][H];
  __shared__ float gates_lds[2][32];
  __shared__ unsigned ready[2][8];
  __shared__ unsigned gcnt[2];
  int g = blockIdx.x;
  int tid = threadIdx.x;
  int G = tid >> 6, l = tid & 63;

  if (tid < 16) ready[tid >> 3][tid & 7] = 0;
  if (tid < 2) gcnt[tid] = 0;
  __syncthreads();

  // one-time weight load: rows G*2048 + g*8 + q, cols j*256 + l*4 + 0..3
  unsigned wpk[8][8][2];
#pragma unroll
  for (int q = 0; q < 8; ++q) {
    const float* wrow = Whh + (size_t)(G * H + g * 8 + q) * H;
#pragma unroll
    for (int j = 0; j < 8; ++j) {
      float4 wv = *(const float4*)(wrow + j * 256 + l * 4);
      wpk[q][j][0] = pk2(wv.x, wv.y);
      wpk[q][j][1] = pk2(wv.z, wv.w);
    }
  }

  float c_state = 0.f;  // valid on wave-0 lanes 0..7
  const unsigned* myrep = hrep + (size_t)(g & 7) * 2 * H;

  for (int t = 0; t < NT; ++t) {
    int p = t & 1;
    unsigned epoch = (unsigned)(t >> 1) + 1u;

    // independent P-row fetch (overlaps everything); wave 0 only
    float p_v = 0.f;
    if (tid < 32)
      p_v = P[(size_t)t * FOURH + (size_t)(tid >> 3) * H + g * 8 + (tid & 7)];

    // ---- own-slice detect -> LDS publish -> block-ready bump ----
    {
      const unsigned* src = myrep + (size_t)p * H + tid * 8;
      unsigned want = ((unsigned)t & 0xffffu) << 16;
      uint4v a, b;
      for (;;) {
        asm volatile(
            "global_load_dwordx4 %0, %2, off sc0 sc1\n\t"
            "global_load_dwordx4 %1, %3, off sc0 sc1\n\t"
            "s_waitcnt vmcnt(0)"
            : "=&v"(a), "=&v"(b)
            : "v"(src), "v"(src + 4)
            : "memory");
        unsigned m = ((a.x ^ want) | (a.y ^ want) | (a.z ^ want) | (a.w ^ want) |
                      (b.x ^ want) | (b.y ^ want) | (b.z ^ want) | (b.w ^ want)) &
                     0xffff0000u;
        if (m == 0) break;
        __builtin_amdgcn_s_sleep(1);
      }
      *(float4*)&h_lds[p][tid * 8] =
          make_float4(__uint_as_float(a.x << 16), __uint_as_float(a.y << 16),
                      __uint_as_float(a.z << 16), __uint_as_float(a.w << 16));
      *(float4*)&h_lds[p][tid * 8 + 4] =
          make_float4(__uint_as_float(b.x << 16), __uint_as_float(b.y << 16),
                      __uint_as_float(b.z << 16), __uint_as_float(b.w << 16));
      __hip_atomic_fetch_add(&ready[p][tid >> 5], 1u, __ATOMIC_RELEASE,
                             __HIP_MEMORY_SCOPE_WORKGROUP);
    }

    // ---- matvec, consuming column-blocks as they become ready ----
    float acc[8] = {0.f, 0.f, 0.f, 0.f, 0.f, 0.f, 0.f, 0.f};
    unsigned bneed = 32u * epoch;
#pragma unroll
    for (int j = 0; j < 8; ++j) {
      while (__hip_atomic_load(&ready[p][j], __ATOMIC_ACQUIRE,
                               __HIP_MEMORY_SCOPE_WORKGROUP) < bneed) {
      }
      float4 hj = *(float4*)&h_lds[p][j * 256 + l * 4];
#pragma unroll
      for (int q = 0; q < 8; ++q) {
        unsigned u0 = wpk[q][j][0], u1 = wpk[q][j][1];
        acc[q] += bflo(u0) * hj.x + bfhi(u0) * hj.y + bflo(u1) * hj.z + bfhi(u1) * hj.w;
      }
    }
    // butterfly reduce over the wave (cols)
#pragma unroll
    for (int q = 0; q < 8; ++q) {
      float v2 = acc[q];
#pragma unroll
      for (int off = 1; off < 64; off <<= 1) v2 += __shfl_xor(v2, off, 64);
      acc[q] = v2;
    }
    if (l == 0) {
#pragma unroll
      for (int q = 0; q < 8; ++q) gates_lds[p][G * 8 + q] = acc[q];
      __hip_atomic_fetch_add(&gcnt[p], 1u, __ATOMIC_RELEASE,
                             __HIP_MEMORY_SCOPE_WORKGROUP);
    }

    // ---- wave 0: gate finish + push to all 8 replicas ----
    if (tid < 64) {
      int q = tid & 7;
      float pre_i = __shfl(p_v, q, 64);
      float pre_f = __shfl(p_v, 8 + q, 64);
      float pre_g = __shfl(p_v, 16 + q, 64);
      float pre_o = __shfl(p_v, 24 + q, 64);
      while (__hip_atomic_load(&gcnt[p], __ATOMIC_ACQUIRE,
                               __HIP_MEMORY_SCOPE_WORKGROUP) < 4u * epoch) {
      }
      unsigned wword = 0;
      if (l < 8) {
        float iv = sigm(gates_lds[p][q]      + pre_i);
        float fv = sigm(gates_lds[p][8 + q]  + pre_f);
        float gv = tanh_fast(gates_lds[p][16 + q] + pre_g);
        float ov = sigm(gates_lds[p][24 + q] + pre_o);
        c_state = fv * c_state + iv * gv;
        float hnew = ov * tanh_fast(c_state);
        wword = ((((unsigned)(t + 1)) & 0xffffu) << 16) | (unsigned)f2bf(hnew);
        int m3 = t - (t / 3) * 3;
        if (m3 == 2) hs[(size_t)(t / 3) * H + g * 8 + q] = hnew;
        if (t == NT - 1) {
          out[512 + g * 8 + q] = hnew;        // hF
          out[512 + H + g * 8 + q] = c_state; // cF
        }
      }
      unsigned w0 = __shfl(wword, 0, 64), w1 = __shfl(wword, 1, 64);
      unsigned w2 = __shfl(wword, 2, 64), w3 = __shfl(wword, 3, 64);
      unsigned w4 = __shfl(wword, 4, 64), w5 = __shfl(wword, 5, 64);
      unsigned w6 = __shfl(wword, 6, 64), w7 = __shfl(wword, 7, 64);
      if (l < 8) {
        unsigned* dst = hrep + ((size_t)l * 2 + ((t + 1) & 1)) * H + g * 8;
        uint4v A, B;
        A.x = w0; A.y = w1; A.z = w2; A.w = w3;
        B.x = w4; B.y = w5; B.z = w6; B.w = w7;
        asm volatile(
            "global_store_dwordx4 %0, %2, off sc0 sc1\n\t"
            "global_store_dwordx4 %1, %3, off sc0 sc1"
            :
            : "v"(dst), "v"(dst + 4), "v"(A), "v"(B)
            : "memory");
      }
    }
  }
}

// ---------------- readout: outputs[256][2] ----------------
__global__ void out_head(const float* __restrict__ hs, const float* __restrict__ Wout,
                         const float* __restrict__ bout, float* __restrict__ out) {
  int s = blockIdx.x;
  int l = threadIdx.x;  // 64
  float a0 = 0.f, a1 = 0.f;
#pragma unroll 4
  for (int j = 0; j < 32; ++j) {
    int idx = j * 64 + l;
    float h = hs[(size_t)s * H + idx];
    a0 += h * Wout[idx];
    a1 += h * Wout[H + idx];
  }
#pragma unroll
  for (int off = 1; off < 64; off <<= 1) {
    a0 += __shfl_xor(a0, off, 64);
    a1 += __shfl_xor(a1, off, 64);
  }
  if (l == 0) {
    out[s * 2]     = a0 + bout[0];
    out[s * 2 + 1] = a1 + bout[1];
  }
}

extern "C" void kernel_launch(void* const* d_in, const int* in_sizes, int n_in,
                              void* d_out, int out_size, void* d_ws, size_t ws_size,
                              hipStream_t stream) {
  const int*   ctx        = (const int*)d_in[0];
  const int*   f1         = (const int*)d_in[1];
  const int*   f2         = (const int*)d_in[2];
  const float* ctx_table  = (const float*)d_in[3];
  const float* face_table = (const float*)d_in[4];
  const float* Wih        = (const float*)d_in[5];
  const float* Whh        = (const float*)d_in[6];
  const float* bih        = (const float*)d_in[7];
  const float* bhh        = (const float*)d_in[8];
  const float* Wout       = (const float*)d_in[9];
  const float* bout       = (const float*)d_in[10];
  float* out = (float*)d_out;

  char* ws = (char*)d_ws;
  size_t off = 0;
  unsigned short* X = (unsigned short*)(ws + off); off += (size_t)NT * H * 2;  // 3,145,728
  float* P    = (float*)(ws + off); off += (size_t)NT * FOURH * 4;             // 25,165,824
  unsigned* hrep = (unsigned*)(ws + off); off += (size_t)8 * 2 * H * 4;        // 131,072
  float* hs   = (float*)(ws + off); off += (size_t)NS * H * 4;                 // 2,097,152

  // zero replicas: parity-0 tag0/value0 = valid t=0 data (h=0); replay-safe
  hipMemsetAsync(hrep, 0, (size_t)8 * 2 * H * 4, stream);

  gather_x<<<NT, 256, 0, stream>>>(ctx, f1, f2, ctx_table, face_table, X);
  gemm_p<<<6 * 64, 256, 0, stream>>>(X, Wih, bih, bhh, P);
  lstm_seq<<<NS, 256, 0, stream>>>(Whh, P, hrep, hs, out);
  out_head<<<NS, 64, 0, stream>>>(hs, Wout, bout, out);
}